// Round 7
// baseline (179.016 us; speedup 1.0000x reference)
//
#include <hip/hip_runtime.h>

typedef unsigned long long ull;
typedef float f32x2 __attribute__((ext_vector_type(2)));
#define FMA2(a,b,c) __builtin_elementwise_fma((a),(b),(c))

#define HH 256
#define WW 256
#define PLANE (HH*WW)
#define TILE_R 32
#define TILE_C 64
#define TT 8
#define ER (TILE_R + 2*TT)   // 48 ext rows
#define EC (TILE_C + 2*TT)   // 80 ext cols
#define NCP (EC/2)           // 40 col-pairs per row
#define NRG 16               // row groups = waves (wave w owns rows 3w..3w+2, lanes 0..39 = colpair)
#define RPT (ER/NRG)         // 3 rows per thread
#define NTHR 1024            // 16 waves (4/SIMD); lanes 40..63 idle in compute, active in staging
#define STRIDE 164           // raw row stride in floats (init staging only)
#define LSZ (4 + ER*STRIDE + 4)   // raw tile for initial staging (~31.5 KB)
#define HROW (NCP*4)         // 160 floats per hsum row-entry
#define HBUFSZ (2*NRG*2*HROW)    // parity x wave x {first,last}: 10240 floats (40 KB)

#define RING_OFS (2u*1024u*1024u)   // float offset of ring slot 1 (8 MB)
#define FLAG_OFS (4u*1024u*1024u)   // float offset of flag array (16 MB)
#define RIMG (HH*(WW/2)*4)          // floats per interleaved ring image (131072)
#define NBLK 256

// DPP cross-lane: VALU pipe. wave_shr:1 = lane n gets lane n-1; wave_shl:1 = lane n gets lane n+1.
// bound_ctrl=true: disabled source lanes give 0 -> lands only on ext-edge columns (ring-0,
// decays before each exchange).
__device__ __forceinline__ float dpp_prev(float v) {
    return __int_as_float(__builtin_amdgcn_update_dpp(0, __float_as_int(v), 0x138, 0xF, 0xF, true));
}
__device__ __forceinline__ float dpp_next(float v) {
    return __int_as_float(__builtin_amdgcn_update_dpp(0, __float_as_int(v), 0x130, 0xF, 0xF, true));
}

// horizontal [1,2,1] sums for one row float4 (u0,v0,u1,v1), u/v packed as f32x2.
__device__ __forceinline__ void hsum2(const float4 M, f32x2& S0, f32x2& S1) {
    f32x2 lo = { M.x, M.y }, hi = { M.z, M.w };
    f32x2 DL = { dpp_prev(M.z), dpp_prev(M.w) };   // left pair's (u1,v1)
    f32x2 DR = { dpp_next(M.x), dpp_next(M.y) };   // right pair's (u0,v0)
    const f32x2 two = 2.0f;
    S0 = FMA2(two, lo, DL) + hi;
    S1 = FMA2(two, hi, lo) + DR;
}

// One Jacobi step, hsum-sharing: publish own first/last-row hsums -> barrier -> consume
// neighbor waves' boundary hsums (clamp at tile edge) -> vertical combine + coupled update.
// State lives ONLY in Mreg; no raw-tile writes (exchange & output go direct from registers).
// Trapezoid: wave inactive at step q when rows ∩ [q-1, 48-q] = ∅ (stale values land only in
// halo rows, overwritten by the direct halo reload before any use).
__device__ __forceinline__ void do_step(
    int q, float* __restrict__ hbuf,
    bool act, int rg, int cp, int r0,
    float4* __restrict__ Mreg,
    const f32x2 (* __restrict__ CA)[2], const f32x2 (* __restrict__ CB)[2],
    const f32x2 (* __restrict__ CC)[2])
{
    const int par = (q - 1) & 1;                       // compile-time with unrolled q
    const bool on = act && (r0 + RPT - 1 >= q - 1) && (r0 <= 48 - q);
    f32x2 S0[RPT+2], S1[RPT+2];

    if (on) {
        #pragma unroll
        for (int j = 0; j < RPT; ++j) hsum2(Mreg[j], S0[j+1], S1[j+1]);
        float* hb = hbuf + (par*NRG + rg)*2*HROW + 4*cp;
        *(float4*)(hb)        = make_float4(S0[1].x,   S0[1].y,   S1[1].x,   S1[1].y);
        *(float4*)(hb + HROW) = make_float4(S0[RPT].x, S0[RPT].y, S1[RPT].x, S1[RPT].y);
    }
    __syncthreads();                                    // uniform: outside all guards
    if (on) {
        if (rg > 0) {
            float4 t = *(const float4*)(hbuf + ((par*NRG + rg-1)*2 + 1)*HROW + 4*cp);
            S0[0] = (f32x2){t.x, t.y}; S1[0] = (f32x2){t.z, t.w};
        } else { S0[0] = S0[1]; S1[0] = S1[1]; }        // clamp = old rm==r0 semantics
        if (rg < NRG-1) {
            float4 t = *(const float4*)(hbuf + ((par*NRG + rg+1)*2 + 0)*HROW + 4*cp);
            S0[RPT+1] = (f32x2){t.x, t.y}; S1[RPT+1] = (f32x2){t.z, t.w};
        } else { S0[RPT+1] = S0[RPT]; S1[RPT+1] = S1[RPT]; }

        const f32x2 two = 2.0f, m4 = -4.0f;
        #pragma unroll
        for (int j = 0; j < RPT; ++j) {
            float4 Mc = Mreg[j];
            f32x2 Mlo = { Mc.x, Mc.y }, Mhi = { Mc.z, Mc.w };
            f32x2 T0 = FMA2(m4, Mlo, FMA2(two, S0[j+1], S0[j]) + S0[j+2]);
            f32x2 T1 = FMA2(m4, Mhi, FMA2(two, S1[j+1], S1[j]) + S1[j+2]);
            f32x2 rr0 = FMA2(CA[j][0], T0, -FMA2(CB[j][0], T0.yx, CC[j][0]));
            f32x2 rr1 = FMA2(CA[j][1], T1, -FMA2(CB[j][1], T1.yx, CC[j][1]));
            Mreg[j] = make_float4(rr0.x, rr0.y, rr1.x, rr1.y);
        }
    }
}

// 16 waves/block, 1 block/CU (grid=256): __launch_bounds__(1024,4) caps VGPR at 128.
__global__ __launch_bounds__(NTHR, 4)
void hs_mega(const float* __restrict__ x,     // (8,3,256,256): It, Ix, Iy
             const float* __restrict__ est,   // (8,2,256,256): u0, v0
             float* __restrict__ out,         // (8,2,256,256)
             float* __restrict__ ws)          // rings (double-buffered) + flags
{
    __shared__ __align__(16) float sraw[LSZ];     // initial staging only
    __shared__ __align__(16) float hbuf[HBUFSZ];  // boundary hsums, parity double-buffered

    const int img = blockIdx.x, cs = blockIdx.y, rb = blockIdx.z;
    const int tid = threadIdx.x;
    const int er0 = rb*TILE_R - TT;
    const int ec0 = cs*TILE_C - TT;
    const int blin = (img*4 + cs)*8 + rb;      // 0..255
    unsigned* flags = (unsigned*)(ws + FLAG_OFS);

    // neighbor block id for the 8 poller threads (same image, 8-neighborhood)
    int nb = -1;
    if (tid < 8) {
        int t = (tid < 4) ? tid : tid + 1;     // skip (0,0)
        int dr = t/3 - 1, dc = t%3 - 1;
        int nrb = rb + dr, ncs = cs + dc;
        if (nrb >= 0 && nrb < 8 && ncs >= 0 && ncs < 4)
            nb = (img*4 + ncs)*8 + nrb;
    }

    // ---- per-thread sweep geometry: wave = row group, lane = colpair ----
    const int cp = tid & 63;           // 0..39 active
    const int rg = tid >> 6;           // 0..15
    const bool act = (cp < NCP);
    const int r0 = rg * RPT;
    const int fb = 4 + 4*cp;

    // ---- per-pixel update coefficients, computed ONCE, packed ----
    // OOB pixels: all-zero coeffs -> update writes exact 0 -> matches reference zero-pad.
    f32x2 CA[RPT][2], CB[RPT][2], CC[RPT][2];
    if (act) {
        const float* __restrict__ xit = x + img*3*PLANE;
        const float* __restrict__ xix = xit + PLANE;
        const float* __restrict__ xiy = xix + PLANE;
        #pragma unroll
        for (int i = 0; i < RPT; ++i) {
            int gr = er0 + r0 + i;
            #pragma unroll
            for (int j = 0; j < 2; ++j) {
                int gc = ec0 + 2*cp + j;
                float A=0.f, B=0.f, C=0.f, D=0.f, E=0.f;
                if (gr >= 0 && gr < HH && gc >= 0 && gc < WW) {
                    int q = gr*WW + gc;
                    float it = xit[q], ix = xix[q], iy = xiy[q];
                    float rd = 1.0f / (1.0f + ix*ix + iy*iy);
                    const float s12 = 1.0f/12.0f;
                    A = (1.0f - ix*ix*rd) * s12;
                    B = (ix*iy*rd) * s12;
                    C = ix*it*rd;
                    D = (1.0f - iy*iy*rd) * s12;
                    E = iy*it*rd;
                }
                CA[i][j] = (f32x2){ A, D };
                CB[i][j] = (f32x2){ B, B };
                CC[i][j] = (f32x2){ C, E };
            }
        }
    }

    // ---- initial full ext-tile stage from est (interleave on the fly; all 1024 threads) ----
    {
        const float* __restrict__ eu = est + img*2*PLANE;
        const float* __restrict__ ev = eu + PLANE;
        for (int k = tid; k < ER*NCP; k += NTHR) {           // 1920 chunks, 2 strides
            int r = k / NCP, c = k - r*NCP;
            int gr = er0 + r, gc = ec0 + 2*c;
            float2 uu = make_float2(0.f,0.f), vv = make_float2(0.f,0.f);
            if (gr >= 0 && gr < HH && gc >= 0 && gc < WW) {
                uu = *(const float2*)(eu + gr*WW + gc);
                vv = *(const float2*)(ev + gr*WW + gc);
            }
            *(float4*)(sraw + 4 + STRIDE*r + 4*c) = make_float4(uu.x, vv.x, uu.y, vv.y);
        }
    }
    __syncthreads();

    // own-row center values live permanently in registers
    float4 Mreg[RPT];
    if (act) {
        #pragma unroll
        for (int j = 0; j < RPT; ++j)
            Mreg[j] = *(const float4*)(sraw + STRIDE*(r0 + j) + fb);
    }

    for (int p = 0; p < 13; ++p) {
        if (p < 12) {
            #pragma unroll
            for (int q = 1; q <= 8; ++q)
                do_step(q, hbuf, act, rg, cp, r0, Mreg, CA, CB, CC);
        } else {
            #pragma unroll
            for (int q = 1; q <= 4; ++q)
                do_step(q, hbuf, act, rg, cp, r0, Mreg, CA, CB, CC);
        }
        // Mreg holds state 8(p+1) (inner region correct; halo stale by design)

        if (p < 12) {
            float* ring = ws + (unsigned)(p & 1) * RING_OFS + img*RIMG;

            // ---- direct reg->ring stores: own annulus cells (same byte set as before) ----
            if (act) {
                #pragma unroll
                for (int j = 0; j < RPT; ++j) {
                    int r = r0 + j;
                    int rr = r - TT, cc = cp - 4;          // inner coords
                    bool inner = (rr >= 0 && rr < TILE_R && cc >= 0 && cc < TILE_C/2);
                    if (inner && (rr < 8 || rr >= TILE_R-8 || cc < 4 || cc >= TILE_C/2-4)) {
                        union { float4 f; ull u[2]; } U; U.f = Mreg[j];
                        float* gp = ring + ((rb*TILE_R + rr)*(WW/2) + cs*(TILE_C/2) + cc)*4;
                        __hip_atomic_store((ull*)gp,     U.u[0], __ATOMIC_RELAXED, __HIP_MEMORY_SCOPE_AGENT);
                        __hip_atomic_store((ull*)gp + 1, U.u[1], __ATOMIC_RELAXED, __HIP_MEMORY_SCOPE_AGENT);
                    }
                }
            }
            asm volatile("s_waitcnt vmcnt(0)" ::: "memory");   // per-wave drain of ring stores
            __syncthreads();
            if (tid == 0)
                __hip_atomic_store(&flags[p*NBLK + blin], 0x5eed0100u + (unsigned)p,
                                   __ATOMIC_RELAXED, __HIP_MEMORY_SCOPE_AGENT);
            asm volatile("" ::: "memory");
            if (tid < 8 && nb >= 0) {
                const unsigned tgt = 0x5eed0100u + (unsigned)p;
                while (__hip_atomic_load(&flags[p*NBLK + nb],
                                         __ATOMIC_RELAXED, __HIP_MEMORY_SCOPE_AGENT) != tgt)
                    __builtin_amdgcn_s_sleep(1);
            }
            __syncthreads();

            // ---- direct ring->reg halo reload: own halo cells (same set as old restage+refresh) ----
            if (act) {
                #pragma unroll
                for (int j = 0; j < RPT; ++j) {
                    int r = r0 + j;
                    if (r < TT || r >= ER-TT || cp < 4 || cp >= NCP-4) {
                        int gr = er0 + r, gc2 = cs*(TILE_C/2) - 4 + cp;
                        if (gr >= 0 && gr < HH && gc2 >= 0 && gc2 < WW/2) {
                            const float* gp = ring + (gr*(WW/2) + gc2)*4;
                            union { float4 f; ull u[2]; } U;
                            U.u[0] = __hip_atomic_load((const ull*)gp,     __ATOMIC_RELAXED, __HIP_MEMORY_SCOPE_AGENT);
                            U.u[1] = __hip_atomic_load((const ull*)gp + 1, __ATOMIC_RELAXED, __HIP_MEMORY_SCOPE_AGENT);
                            Mreg[j] = U.f;
                        } else {
                            Mreg[j] = make_float4(0.f, 0.f, 0.f, 0.f);
                        }
                    }
                }
            }
        }
    }

    // ---- final: planar output straight from registers (inner cells) ----
    {
        float* ou = out + img*2*PLANE;
        float* ov = ou + PLANE;
        if (act) {
            #pragma unroll
            for (int j = 0; j < RPT; ++j) {
                int r = r0 + j;
                int rr = r - TT, cc = cp - 4;
                if (rr >= 0 && rr < TILE_R && cc >= 0 && cc < TILE_C/2) {
                    int qq = (rb*TILE_R + rr)*WW + cs*TILE_C + 2*cc;
                    *(float2*)(ou + qq) = make_float2(Mreg[j].x, Mreg[j].z);
                    *(float2*)(ov + qq) = make_float2(Mreg[j].y, Mreg[j].w);
                }
            }
        }
    }
}

extern "C" void kernel_launch(void* const* d_in, const int* in_sizes, int n_in,
                              void* d_out, int out_size, void* d_ws, size_t ws_size,
                              hipStream_t stream) {
    const float* x   = (const float*)d_in[0];   // (8,3,256,256) fp32
    const float* est = (const float*)d_in[1];   // (8,2,256,256) fp32
    float* out = (float*)d_out;
    float* ws  = (float*)d_ws;                  // ring slot0 @0, slot1 @8MB, flags @16MB
                                                // flags 0xAA-poisoned each launch: != MAGIC, no reset needed

    dim3 grid(8, WW/TILE_C, HH/TILE_R);         // 256 blocks, all co-resident (1/CU: ~72.5KB LDS, 16 waves)
    dim3 blk(NTHR);
    hs_mega<<<grid, blk, 0, stream>>>(x, est, out, ws);
}

// Round 8
// 168.942 us; speedup vs baseline: 1.0596x; 1.0596x over previous
//
#include <hip/hip_runtime.h>

typedef unsigned long long ull;
typedef float f32x2 __attribute__((ext_vector_type(2)));
#define FMA2(a,b,c) __builtin_elementwise_fma((a),(b),(c))

#define HH 256
#define WW 256
#define PLANE (HH*WW)
#define TILE_R 32
#define TILE_C 64
#define TT 16                // halo depth = steps per phase: 6 exchanges (100 = 6*16 + 4)
#define ER (TILE_R + 2*TT)   // 64 ext rows
#define EC (TILE_C + 2*TT)   // 96 ext cols
#define NCP (EC/2)           // 48 col-pairs per row (48 of 64 lanes active)
#define NRG 16               // row groups = waves (wave w owns rows 4w..4w+3)
#define RPT (ER/NRG)         // 4 rows per thread
#define NTHR 1024            // 16 waves (4/SIMD)
#define STRIDE 196           // init-staging row stride: 4 front-pad + 192
#define LSZ (4 + ER*STRIDE + 4)    // 12552 floats — smem high-water mark
#define HROW (NCP*4)         // 192 floats per hsum row-entry
#define HBUFSZ (2*NRG*2*HROW)      // 12288 floats (fits under LSZ)
// xbuf (exchange staging): inner 4096 floats / halo 8192 floats — also under LSZ

#define RING_OFS (2u*1024u*1024u)  // float offset of ring slot 1 (8 MB)
#define FLAG_OFS (4u*1024u*1024u)  // float offset of flag array (16 MB)
#define RIMG (HH*(WW/2)*4)         // floats per interleaved ring image
#define NBLK 256
#define NHALO (ER*NCP - TILE_R*(TILE_C/2))   // 2048 halo cells

// DPP cross-lane: VALU pipe. wave_shr:1 = lane n gets lane n-1; wave_shl:1 = lane n gets n+1.
// bound_ctrl=true: disabled-lane sources give 0 -> lands only on ext-edge columns; edge
// corruption moves 1 col/step -> reaches col 15 at step 16 = halo edge, never inner.
__device__ __forceinline__ float dpp_prev(float v) {
    return __int_as_float(__builtin_amdgcn_update_dpp(0, __float_as_int(v), 0x138, 0xF, 0xF, true));
}
__device__ __forceinline__ float dpp_next(float v) {
    return __int_as_float(__builtin_amdgcn_update_dpp(0, __float_as_int(v), 0x130, 0xF, 0xF, true));
}

// horizontal [1,2,1] sums for one row float4 (u0,v0,u1,v1), u/v packed as f32x2.
__device__ __forceinline__ void hsum2(const float4 M, f32x2& S0, f32x2& S1) {
    f32x2 lo = { M.x, M.y }, hi = { M.z, M.w };
    f32x2 DL = { dpp_prev(M.z), dpp_prev(M.w) };
    f32x2 DR = { dpp_next(M.x), dpp_next(M.y) };
    const f32x2 two = 2.0f;
    S0 = FMA2(two, lo, DL) + hi;
    S1 = FMA2(two, hi, lo) + DR;
}

// One Jacobi step (state only in Mreg): publish own first/last-row hsums -> barrier ->
// consume neighbor waves' boundary hsums (clamp at tile edge) -> vertical + coupled update.
// Trapezoid: wave on iff rows ∩ [q-1, ER-q] ≠ ∅ — 1-row slack over the true cone [q, ER-1-q]
// absorbs the stale-parity boundary row (same invariant verified bit-exact at TT=8).
__device__ __forceinline__ void do_step(
    int q, float* __restrict__ hbuf,
    bool act, int rg, int cp, int r0,
    float4* __restrict__ Mreg,
    const f32x2 (* __restrict__ CA)[2], const f32x2 (* __restrict__ CB)[2],
    const f32x2 (* __restrict__ CC)[2])
{
    const int par = (q - 1) & 1;
    const bool on = act && (r0 + RPT - 1 >= q - 1) && (r0 <= ER - q);
    f32x2 S0[RPT+2], S1[RPT+2];

    if (on) {
        #pragma unroll
        for (int j = 0; j < RPT; ++j) hsum2(Mreg[j], S0[j+1], S1[j+1]);
        float* hb = hbuf + (par*NRG + rg)*2*HROW + 4*cp;
        *(float4*)(hb)        = make_float4(S0[1].x,   S0[1].y,   S1[1].x,   S1[1].y);
        *(float4*)(hb + HROW) = make_float4(S0[RPT].x, S0[RPT].y, S1[RPT].x, S1[RPT].y);
    }
    __syncthreads();                                    // uniform: outside all guards
    if (on) {
        if (rg > 0) {
            float4 t = *(const float4*)(hbuf + ((par*NRG + rg-1)*2 + 1)*HROW + 4*cp);
            S0[0] = (f32x2){t.x, t.y}; S1[0] = (f32x2){t.z, t.w};
        } else { S0[0] = S0[1]; S1[0] = S1[1]; }        // clamp at ext-tile edge
        if (rg < NRG-1) {
            float4 t = *(const float4*)(hbuf + ((par*NRG + rg+1)*2 + 0)*HROW + 4*cp);
            S0[RPT+1] = (f32x2){t.x, t.y}; S1[RPT+1] = (f32x2){t.z, t.w};
        } else { S0[RPT+1] = S0[RPT]; S1[RPT+1] = S1[RPT]; }

        const f32x2 two = 2.0f, m4 = -4.0f;
        #pragma unroll
        for (int j = 0; j < RPT; ++j) {
            float4 Mc = Mreg[j];
            f32x2 Mlo = { Mc.x, Mc.y }, Mhi = { Mc.z, Mc.w };
            f32x2 T0 = FMA2(m4, Mlo, FMA2(two, S0[j+1], S0[j]) + S0[j+2]);
            f32x2 T1 = FMA2(m4, Mhi, FMA2(two, S1[j+1], S1[j]) + S1[j+2]);
            f32x2 rr0 = FMA2(CA[j][0], T0, -FMA2(CB[j][0], T0.yx, CC[j][0]));
            f32x2 rr1 = FMA2(CA[j][1], T1, -FMA2(CB[j][1], T1.yx, CC[j][1]));
            Mreg[j] = make_float4(rr0.x, rr0.y, rr1.x, rr1.y);
        }
    }
}

// halo-cell linear index (also the restage loop's k-mapping); r = ext row, cp = colpair
__device__ __forceinline__ int halo_idx(int r, int cp) {
    if (r < TT)       return r*NCP + cp;
    if (r >= ER-TT)   return TT*NCP + (r-(ER-TT))*NCP + cp;
    return 2*TT*NCP + (r-TT)*(2*(TT/2)) + ((cp < TT/2) ? cp : cp - (NCP-TT/2) + TT/2);
}

// 16 waves/block, 1 block/CU (grid=256): __launch_bounds__(1024,4) caps VGPR at 128.
__global__ __launch_bounds__(NTHR, 4)
void hs_mega(const float* __restrict__ x,     // (8,3,256,256): It, Ix, Iy
             const float* __restrict__ est,   // (8,2,256,256): u0, v0
             float* __restrict__ out,         // (8,2,256,256)
             float* __restrict__ ws)          // rings (double-buffered) + flags
{
    // single smem arena, time-sliced (barrier-separated): init staging / hsum buf / exchange buf
    __shared__ __align__(16) float smem[LSZ];
    float* const sraw = smem;     // init staging only
    float* const hbuf = smem;     // during step phases
    float* const xbuf = smem;     // during exchanges + epilogue

    const int img = blockIdx.x, cs = blockIdx.y, rb = blockIdx.z;
    const int tid = threadIdx.x;
    const int er0 = rb*TILE_R - TT;
    const int ec0 = cs*TILE_C - TT;
    const int blin = (img*4 + cs)*8 + rb;      // 0..255
    unsigned* flags = (unsigned*)(ws + FLAG_OFS);

    // neighbor block id for the 8 poller threads (same image, 8-neighborhood)
    int nb = -1;
    if (tid < 8) {
        int t = (tid < 4) ? tid : tid + 1;     // skip (0,0)
        int dr = t/3 - 1, dc = t%3 - 1;
        int nrb = rb + dr, ncs = cs + dc;
        if (nrb >= 0 && nrb < 8 && ncs >= 0 && ncs < 4)
            nb = (img*4 + ncs)*8 + nrb;
    }

    // ---- per-thread sweep geometry: wave = row group, lane = colpair ----
    const int cp = tid & 63;           // 0..47 active
    const int rg = tid >> 6;           // 0..15
    const bool act = (cp < NCP);
    const int r0 = rg * RPT;
    const int fb = 4 + 4*cp;

    // ---- per-pixel update coefficients, computed ONCE, packed ----
    // OOB pixels: all-zero coeffs -> update writes exact 0 -> matches reference zero-pad.
    f32x2 CA[RPT][2], CB[RPT][2], CC[RPT][2];
    if (act) {
        const float* __restrict__ xit = x + img*3*PLANE;
        const float* __restrict__ xix = xit + PLANE;
        const float* __restrict__ xiy = xix + PLANE;
        #pragma unroll
        for (int i = 0; i < RPT; ++i) {
            int gr = er0 + r0 + i;
            #pragma unroll
            for (int j = 0; j < 2; ++j) {
                int gc = ec0 + 2*cp + j;
                float A=0.f, B=0.f, C=0.f, D=0.f, E=0.f;
                if (gr >= 0 && gr < HH && gc >= 0 && gc < WW) {
                    int q = gr*WW + gc;
                    float it = xit[q], ix = xix[q], iy = xiy[q];
                    float rd = 1.0f / (1.0f + ix*ix + iy*iy);
                    const float s12 = 1.0f/12.0f;
                    A = (1.0f - ix*ix*rd) * s12;
                    B = (ix*iy*rd) * s12;
                    C = ix*it*rd;
                    D = (1.0f - iy*iy*rd) * s12;
                    E = iy*it*rd;
                }
                CA[i][j] = (f32x2){ A, D };
                CB[i][j] = (f32x2){ B, B };
                CC[i][j] = (f32x2){ C, E };
            }
        }
    }

    // ---- initial full ext-tile stage from est (interleave on the fly; all threads) ----
    {
        const float* __restrict__ eu = est + img*2*PLANE;
        const float* __restrict__ ev = eu + PLANE;
        for (int k = tid; k < ER*NCP; k += NTHR) {           // 3072 chunks, 3 strides
            int r = k / NCP, c = k - r*NCP;
            int gr = er0 + r, gc = ec0 + 2*c;
            float2 uu = make_float2(0.f,0.f), vv = make_float2(0.f,0.f);
            if (gr >= 0 && gr < HH && gc >= 0 && gc < WW) {
                uu = *(const float2*)(eu + gr*WW + gc);
                vv = *(const float2*)(ev + gr*WW + gc);
            }
            *(float4*)(sraw + 4 + STRIDE*r + 4*c) = make_float4(uu.x, vv.x, uu.y, vv.y);
        }
    }
    __syncthreads();

    float4 Mreg[RPT];
    if (act) {
        #pragma unroll
        for (int j = 0; j < RPT; ++j)
            Mreg[j] = *(const float4*)(sraw + STRIDE*(r0 + j) + fb);
    }
    __syncthreads();   // sraw reads done before step-1 publish reuses the arena

    for (int p = 0; p < 7; ++p) {
        if (p < 6) {
            #pragma unroll
            for (int q = 1; q <= 16; ++q)
                do_step(q, hbuf, act, rg, cp, r0, Mreg, CA, CB, CC);
        } else {
            #pragma unroll
            for (int q = 1; q <= 4; ++q)
                do_step(q, hbuf, act, rg, cp, r0, Mreg, CA, CB, CC);
        }

        if (p < 6) {
            float* ring = ws + (unsigned)(p & 1) * RING_OFS + img*RIMG;

            __syncthreads();   // all hbuf reads done before xbuf writes (arena alias)
            // ---- Mreg -> compact xbuf (depth-16 annulus of 32x64 = the whole inner tile) ----
            if (act) {
                #pragma unroll
                for (int j = 0; j < RPT; ++j) {
                    int rr = r0 + j - TT, cc = cp - TT/2;   // inner coords
                    if (rr >= 0 && rr < TILE_R && cc >= 0 && cc < TILE_C/2)
                        *(float4*)(xbuf + 4*(rr*(TILE_C/2) + cc)) = Mreg[j];
                }
            }
            __syncthreads();
            // ---- coalesced ring store of inner tile (coherent 8B stores) ----
            for (int k = tid; k < TILE_R*(TILE_C/2); k += NTHR) {   // 1024, 1 stride
                int r = k >> 5, c2 = k & 31;
                const float* sp = xbuf + 4*k;
                float* gp = ring + ((rb*TILE_R + r)*(WW/2) + cs*(TILE_C/2) + c2)*4;
                __hip_atomic_store((ull*)gp,     *(const ull*)sp,       __ATOMIC_RELAXED, __HIP_MEMORY_SCOPE_AGENT);
                __hip_atomic_store((ull*)gp + 1, *(const ull*)(sp + 2), __ATOMIC_RELAXED, __HIP_MEMORY_SCOPE_AGENT);
            }
            asm volatile("s_waitcnt vmcnt(0)" ::: "memory");   // per-wave drain
            __syncthreads();
            if (tid == 0)
                __hip_atomic_store(&flags[p*NBLK + blin], 0x5eed0100u + (unsigned)p,
                                   __ATOMIC_RELAXED, __HIP_MEMORY_SCOPE_AGENT);
            asm volatile("" ::: "memory");
            if (tid < 8 && nb >= 0) {
                const unsigned tgt = 0x5eed0100u + (unsigned)p;
                while (__hip_atomic_load(&flags[p*NBLK + nb],
                                         __ATOMIC_RELAXED, __HIP_MEMORY_SCOPE_AGENT) != tgt)
                    __builtin_amdgcn_s_sleep(1);
            }
            __syncthreads();

            // ---- coalesced restage of ext halo into xbuf (coherent 8B loads) ----
            for (int k = tid; k < NHALO; k += NTHR) {              // 2048, 2 strides
                int r, c2;
                if (k < TT*NCP)            { r = k / NCP;                 c2 = k - (k/NCP)*NCP; }
                else if (k < 2*TT*NCP)     { int m = k - TT*NCP; r = (ER-TT) + m/NCP; c2 = m - (m/NCP)*NCP; }
                else { int m = k - 2*TT*NCP; r = TT + m/TT; int t = m % TT; c2 = (t < TT/2) ? t : (NCP-TT/2) + (t-TT/2); }
                int gr = er0 + r, gc2 = cs*(TILE_C/2) - TT/2 + c2;
                ull v0 = 0, v1 = 0;
                if (gr >= 0 && gr < HH && gc2 >= 0 && gc2 < WW/2) {
                    const float* gp = ring + (gr*(WW/2) + gc2)*4;
                    v0 = __hip_atomic_load((const ull*)gp,     __ATOMIC_RELAXED, __HIP_MEMORY_SCOPE_AGENT);
                    v1 = __hip_atomic_load((const ull*)gp + 1, __ATOMIC_RELAXED, __HIP_MEMORY_SCOPE_AGENT);
                }
                float* sp = xbuf + 4*k;
                *(ull*)sp = v0;
                *(ull*)(sp + 2) = v1;
            }
            __syncthreads();
            // ---- refresh carried centers for own halo cells ----
            if (act) {
                #pragma unroll
                for (int j = 0; j < RPT; ++j) {
                    int r = r0 + j;
                    if (r < TT || r >= ER-TT || cp < TT/2 || cp >= NCP-TT/2)
                        Mreg[j] = *(const float4*)(xbuf + 4*halo_idx(r, cp));
                }
            }
            __syncthreads();   // refresh reads done before next phase's publish (arena alias)
        }
    }

    // ---- final: Mreg -> xbuf -> coalesced planar output ----
    __syncthreads();   // hbuf reads done (arena alias)
    if (act) {
        #pragma unroll
        for (int j = 0; j < RPT; ++j) {
            int rr = r0 + j - TT, cc = cp - TT/2;
            if (rr >= 0 && rr < TILE_R && cc >= 0 && cc < TILE_C/2)
                *(float4*)(xbuf + 4*(rr*(TILE_C/2) + cc)) = Mreg[j];
        }
    }
    __syncthreads();
    {
        float* ou = out + img*2*PLANE;
        float* ov = ou + PLANE;
        for (int k = tid; k < TILE_R*(TILE_C/2); k += NTHR) {
            int r = k >> 5, c2 = k & 31;
            float4 V = *(const float4*)(xbuf + 4*k);
            int q = (rb*TILE_R + r)*WW + cs*TILE_C + 2*c2;
            *(float2*)(ou + q) = make_float2(V.x, V.z);
            *(float2*)(ov + q) = make_float2(V.y, V.w);
        }
    }
}

extern "C" void kernel_launch(void* const* d_in, const int* in_sizes, int n_in,
                              void* d_out, int out_size, void* d_ws, size_t ws_size,
                              hipStream_t stream) {
    const float* x   = (const float*)d_in[0];   // (8,3,256,256) fp32
    const float* est = (const float*)d_in[1];   // (8,2,256,256) fp32
    float* out = (float*)d_out;
    float* ws  = (float*)d_ws;                  // ring slot0 @0, slot1 @8MB, flags @16MB
                                                // flags 0xAA-poisoned each launch: != MAGIC

    dim3 grid(8, WW/TILE_C, HH/TILE_R);         // 256 blocks, all co-resident (1/CU: ~49KB LDS, 16 waves)
    dim3 blk(NTHR);
    hs_mega<<<grid, blk, 0, stream>>>(x, est, out, ws);
}

// Round 10
// 164.902 us; speedup vs baseline: 1.0856x; 1.0245x over previous
//
#include <hip/hip_runtime.h>

typedef unsigned long long ull;
typedef float f32x2 __attribute__((ext_vector_type(2)));
#define FMA2(a,b,c) __builtin_elementwise_fma((a),(b),(c))

#define HH 256
#define WW 256
#define PLANE (HH*WW)
#define TILE_R 32
#define TILE_C 64
#define TT 16                // halo depth = steps per phase: 6 exchanges (100 = 6*16 + 4)
#define ER (TILE_R + 2*TT)   // 64 ext rows
#define EC (TILE_C + 2*TT)   // 96 ext cols
#define NCP (EC/2)           // 48 col-pairs per row (48 of 64 lanes active)
#define NRG 16               // row groups = waves (wave w owns rows 4w..4w+3)
#define RPT (ER/NRG)         // 4 rows per thread
#define NTHR 1024            // 16 waves (4/SIMD)
#define STRIDE 196           // init-staging row stride: 4 front-pad + 192
#define LSZ (4 + ER*STRIDE + 4)    // 12552 floats — sraw/hbuf arena
#define HROW (NCP*4)         // 192 floats per hsum row-entry
#define HBUFSZ (2*NRG*2*HROW)      // 12288 floats (fits under LSZ)
#define XBUFSZ (2048*4)      // dedicated exchange/output staging: 8192 floats (32 KB)

#define RING_OFS (2u*1024u*1024u)  // float offset of ring slot 1 (8 MB)
#define FLAG_OFS (4u*1024u*1024u)  // float offset of flag array (16 MB)
#define RIMG (HH*(WW/2)*4)         // floats per interleaved ring image
#define NBLK 256
#define NHALO (ER*NCP - TILE_R*(TILE_C/2))   // 2048 halo cells

// DPP cross-lane: VALU pipe. wave_shr:1 = lane n gets lane n-1; wave_shl:1 = lane n gets n+1.
// bound_ctrl=true: disabled-lane sources give 0 -> lands only on ext-edge columns; edge
// corruption moves 1 col/step -> reaches col 15 at step 16 = halo edge, never inner.
__device__ __forceinline__ float dpp_prev(float v) {
    return __int_as_float(__builtin_amdgcn_update_dpp(0, __float_as_int(v), 0x138, 0xF, 0xF, true));
}
__device__ __forceinline__ float dpp_next(float v) {
    return __int_as_float(__builtin_amdgcn_update_dpp(0, __float_as_int(v), 0x130, 0xF, 0xF, true));
}

// horizontal [1,2,1] sums for one row float4 (u0,v0,u1,v1), u/v packed as f32x2.
__device__ __forceinline__ void hsum2(const float4 M, f32x2& S0, f32x2& S1) {
    f32x2 lo = { M.x, M.y }, hi = { M.z, M.w };
    f32x2 DL = { dpp_prev(M.z), dpp_prev(M.w) };
    f32x2 DR = { dpp_next(M.x), dpp_next(M.y) };
    const f32x2 two = 2.0f;
    S0 = FMA2(two, lo, DL) + hi;
    S1 = FMA2(two, hi, lo) + DR;
}

// One Jacobi step (state only in Mreg): publish own first/last-row hsums -> barrier ->
// consume neighbor waves' boundary hsums (clamp at tile edge) -> vertical + coupled update.
// Trapezoid: wave on iff rows ∩ [q-1, ER-q] ≠ ∅ — 1-row slack over the true cone [q, ER-1-q]
// absorbs the stale-parity boundary row (invariant verified bit-exact at TT=8 and TT=16).
__device__ __forceinline__ void do_step(
    int q, float* __restrict__ hbuf,
    bool act, int rg, int cp, int r0,
    float4* __restrict__ Mreg,
    const f32x2 (* __restrict__ CA)[2], const f32x2 (* __restrict__ CB)[2],
    const f32x2 (* __restrict__ CC)[2])
{
    const int par = (q - 1) & 1;
    const bool on = act && (r0 + RPT - 1 >= q - 1) && (r0 <= ER - q);
    f32x2 S0[RPT+2], S1[RPT+2];

    if (on) {
        #pragma unroll
        for (int j = 0; j < RPT; ++j) hsum2(Mreg[j], S0[j+1], S1[j+1]);
        float* hb = hbuf + (par*NRG + rg)*2*HROW + 4*cp;
        *(float4*)(hb)        = make_float4(S0[1].x,   S0[1].y,   S1[1].x,   S1[1].y);
        *(float4*)(hb + HROW) = make_float4(S0[RPT].x, S0[RPT].y, S1[RPT].x, S1[RPT].y);
    }
    __syncthreads();                                    // uniform: outside all guards
    if (on) {
        if (rg > 0) {
            float4 t = *(const float4*)(hbuf + ((par*NRG + rg-1)*2 + 1)*HROW + 4*cp);
            S0[0] = (f32x2){t.x, t.y}; S1[0] = (f32x2){t.z, t.w};
        } else { S0[0] = S0[1]; S1[0] = S1[1]; }        // clamp at ext-tile edge
        if (rg < NRG-1) {
            float4 t = *(const float4*)(hbuf + ((par*NRG + rg+1)*2 + 0)*HROW + 4*cp);
            S0[RPT+1] = (f32x2){t.x, t.y}; S1[RPT+1] = (f32x2){t.z, t.w};
        } else { S0[RPT+1] = S0[RPT]; S1[RPT+1] = S1[RPT]; }

        const f32x2 two = 2.0f, m4 = -4.0f;
        #pragma unroll
        for (int j = 0; j < RPT; ++j) {
            float4 Mc = Mreg[j];
            f32x2 Mlo = { Mc.x, Mc.y }, Mhi = { Mc.z, Mc.w };
            f32x2 T0 = FMA2(m4, Mlo, FMA2(two, S0[j+1], S0[j]) + S0[j+2]);
            f32x2 T1 = FMA2(m4, Mhi, FMA2(two, S1[j+1], S1[j]) + S1[j+2]);
            f32x2 rr0 = FMA2(CA[j][0], T0, -FMA2(CB[j][0], T0.yx, CC[j][0]));
            f32x2 rr1 = FMA2(CA[j][1], T1, -FMA2(CB[j][1], T1.yx, CC[j][1]));
            Mreg[j] = make_float4(rr0.x, rr0.y, rr1.x, rr1.y);
        }
    }
}

// halo-cell linear index (also the restage loop's k-mapping); r = ext row, cp = colpair
__device__ __forceinline__ int halo_idx(int r, int cp) {
    if (r < TT)       return r*NCP + cp;
    if (r >= ER-TT)   return TT*NCP + (r-(ER-TT))*NCP + cp;
    return 2*TT*NCP + (r-TT)*(2*(TT/2)) + ((cp < TT/2) ? cp : cp - (NCP-TT/2) + TT/2);
}

// 16 waves/block, 1 block/CU (grid=256): __launch_bounds__(1024,4) caps VGPR at 128.
__global__ __launch_bounds__(NTHR, 4)
void hs_mega(const float* __restrict__ x,     // (8,3,256,256): It, Ix, Iy
             const float* __restrict__ est,   // (8,2,256,256): u0, v0
             float* __restrict__ out,         // (8,2,256,256)
             float* __restrict__ ws)          // rings (double-buffered) + flags
{
    // smem arena (init staging / hsum buf alias) + DEDICATED exchange/output staging.
    // Separate xbuf kills the 2 alias barriers per exchange (+1 at final) that r8 needed.
    __shared__ __align__(16) float smem[LSZ];
    __shared__ __align__(16) float xbuf[XBUFSZ];
    float* const sraw = smem;     // init staging only
    float* const hbuf = smem;     // during step phases

    const int img = blockIdx.x, cs = blockIdx.y, rb = blockIdx.z;
    const int tid = threadIdx.x;
    const int er0 = rb*TILE_R - TT;
    const int ec0 = cs*TILE_C - TT;
    const int blin = (img*4 + cs)*8 + rb;      // 0..255
    unsigned* flags = (unsigned*)(ws + FLAG_OFS);

    // neighbor block id for the 8 poller threads (same image, 8-neighborhood)
    int nb = -1;
    if (tid < 8) {
        int t = (tid < 4) ? tid : tid + 1;     // skip (0,0)
        int dr = t/3 - 1, dc = t%3 - 1;
        int nrb = rb + dr, ncs = cs + dc;
        if (nrb >= 0 && nrb < 8 && ncs >= 0 && ncs < 4)
            nb = (img*4 + ncs)*8 + nrb;
    }

    // ---- per-thread sweep geometry: wave = row group, lane = colpair ----
    const int cp = tid & 63;           // 0..47 active
    const int rg = tid >> 6;           // 0..15
    const bool act = (cp < NCP);
    const int r0 = rg * RPT;
    const int fb = 4 + 4*cp;

    // ---- per-pixel update coefficients, computed ONCE, packed; float2 plane loads ----
    // gc0 = ec0+2cp is even -> the (gc0, gc0+1) pair is in/out of bounds atomically.
    // OOB pixels MUST get all-zero coeffs (zero-pad contract): loads give it=ix=iy=0, and
    // the `one` factor (0 when OOB) zeroes A and D too (r9 bug: A=D=1/12 when OOB).
    f32x2 CA[RPT][2], CB[RPT][2], CC[RPT][2];
    if (act) {
        const float* __restrict__ xit = x + img*3*PLANE;
        const float* __restrict__ xix = xit + PLANE;
        const float* __restrict__ xiy = xix + PLANE;
        const int gc0 = ec0 + 2*cp;
        #pragma unroll
        for (int i = 0; i < RPT; ++i) {
            int gr = er0 + r0 + i;
            bool inb = (gr >= 0 && gr < HH && gc0 >= 0 && gc0 < WW);
            float one = inb ? 1.0f : 0.0f;
            float2 it2 = make_float2(0.f,0.f), ix2 = make_float2(0.f,0.f), iy2 = make_float2(0.f,0.f);
            if (inb) {
                int q = gr*WW + gc0;
                it2 = *(const float2*)(xit + q);
                ix2 = *(const float2*)(xix + q);
                iy2 = *(const float2*)(xiy + q);
            }
            #pragma unroll
            for (int j = 0; j < 2; ++j) {
                float it = (j == 0) ? it2.x : it2.y;
                float ix = (j == 0) ? ix2.x : ix2.y;
                float iy = (j == 0) ? iy2.x : iy2.y;
                float rd = 1.0f / (1.0f + ix*ix + iy*iy);
                const float s12 = 1.0f/12.0f;
                float A = (one - ix*ix*rd) * s12;   // OOB: one=0, ix=0 -> A=0
                float B = (ix*iy*rd) * s12;         // OOB: 0
                float C = ix*it*rd;                 // OOB: 0
                float D = (one - iy*iy*rd) * s12;   // OOB: 0
                float E = iy*it*rd;                 // OOB: 0
                CA[i][j] = (f32x2){ A, D };
                CB[i][j] = (f32x2){ B, B };
                CC[i][j] = (f32x2){ C, E };
            }
        }
    }

    // ---- initial full ext-tile stage from est (interleave on the fly; all threads) ----
    {
        const float* __restrict__ eu = est + img*2*PLANE;
        const float* __restrict__ ev = eu + PLANE;
        for (int k = tid; k < ER*NCP; k += NTHR) {           // 3072 chunks, 3 strides
            int r = k / NCP, c = k - r*NCP;
            int gr = er0 + r, gc = ec0 + 2*c;
            float2 uu = make_float2(0.f,0.f), vv = make_float2(0.f,0.f);
            if (gr >= 0 && gr < HH && gc >= 0 && gc < WW) {
                uu = *(const float2*)(eu + gr*WW + gc);
                vv = *(const float2*)(ev + gr*WW + gc);
            }
            *(float4*)(sraw + 4 + STRIDE*r + 4*c) = make_float4(uu.x, vv.x, uu.y, vv.y);
        }
    }
    __syncthreads();

    float4 Mreg[RPT];
    if (act) {
        #pragma unroll
        for (int j = 0; j < RPT; ++j)
            Mreg[j] = *(const float4*)(sraw + STRIDE*(r0 + j) + fb);
    }
    __syncthreads();   // sraw reads done before step-1 publish reuses the arena (hbuf alias)

    for (int p = 0; p < 7; ++p) {
        if (p < 6) {
            #pragma unroll
            for (int q = 1; q <= 16; ++q)
                do_step(q, hbuf, act, rg, cp, r0, Mreg, CA, CB, CC);
        } else {
            #pragma unroll
            for (int q = 1; q <= 4; ++q)
                do_step(q, hbuf, act, rg, cp, r0, Mreg, CA, CB, CC);
        }

        if (p < 6) {
            float* ring = ws + (unsigned)(p & 1) * RING_OFS + img*RIMG;

            // ---- Mreg -> xbuf (dedicated buffer: no alias barrier needed) ----
            if (act) {
                #pragma unroll
                for (int j = 0; j < RPT; ++j) {
                    int rr = r0 + j - TT, cc = cp - TT/2;   // inner coords
                    if (rr >= 0 && rr < TILE_R && cc >= 0 && cc < TILE_C/2)
                        *(float4*)(xbuf + 4*(rr*(TILE_C/2) + cc)) = Mreg[j];
                }
            }
            __syncthreads();
            // ---- coalesced ring store of inner tile (coherent 8B stores) ----
            for (int k = tid; k < TILE_R*(TILE_C/2); k += NTHR) {   // 1024, 1 stride
                int r = k >> 5, c2 = k & 31;
                const float* sp = xbuf + 4*k;
                float* gp = ring + ((rb*TILE_R + r)*(WW/2) + cs*(TILE_C/2) + c2)*4;
                __hip_atomic_store((ull*)gp,     *(const ull*)sp,       __ATOMIC_RELAXED, __HIP_MEMORY_SCOPE_AGENT);
                __hip_atomic_store((ull*)gp + 1, *(const ull*)(sp + 2), __ATOMIC_RELAXED, __HIP_MEMORY_SCOPE_AGENT);
            }
            asm volatile("s_waitcnt vmcnt(0)" ::: "memory");   // per-wave drain
            __syncthreads();
            if (tid == 0)
                __hip_atomic_store(&flags[p*NBLK + blin], 0x5eed0100u + (unsigned)p,
                                   __ATOMIC_RELAXED, __HIP_MEMORY_SCOPE_AGENT);
            asm volatile("" ::: "memory");
            if (tid < 8 && nb >= 0) {
                const unsigned tgt = 0x5eed0100u + (unsigned)p;
                while (__hip_atomic_load(&flags[p*NBLK + nb],
                                         __ATOMIC_RELAXED, __HIP_MEMORY_SCOPE_AGENT) != tgt)
                    __builtin_amdgcn_s_sleep(1);
            }
            __syncthreads();

            // ---- coalesced restage of ext halo into xbuf (coherent 8B loads) ----
            for (int k = tid; k < NHALO; k += NTHR) {              // 2048, 2 strides
                int r, c2;
                if (k < TT*NCP)            { r = k / NCP;                 c2 = k - (k/NCP)*NCP; }
                else if (k < 2*TT*NCP)     { int m = k - TT*NCP; r = (ER-TT) + m/NCP; c2 = m - (m/NCP)*NCP; }
                else { int m = k - 2*TT*NCP; r = TT + m/TT; int t = m % TT; c2 = (t < TT/2) ? t : (NCP-TT/2) + (t-TT/2); }
                int gr = er0 + r, gc2 = cs*(TILE_C/2) - TT/2 + c2;
                ull v0 = 0, v1 = 0;
                if (gr >= 0 && gr < HH && gc2 >= 0 && gc2 < WW/2) {
                    const float* gp = ring + (gr*(WW/2) + gc2)*4;
                    v0 = __hip_atomic_load((const ull*)gp,     __ATOMIC_RELAXED, __HIP_MEMORY_SCOPE_AGENT);
                    v1 = __hip_atomic_load((const ull*)gp + 1, __ATOMIC_RELAXED, __HIP_MEMORY_SCOPE_AGENT);
                }
                float* sp = xbuf + 4*k;
                *(ull*)sp = v0;
                *(ull*)(sp + 2) = v1;
            }
            __syncthreads();
            // ---- refresh carried centers for own halo cells (xbuf: no alias with hbuf,
            //      so NO trailing barrier needed before next phase's publish) ----
            if (act) {
                #pragma unroll
                for (int j = 0; j < RPT; ++j) {
                    int r = r0 + j;
                    if (r < TT || r >= ER-TT || cp < TT/2 || cp >= NCP-TT/2)
                        Mreg[j] = *(const float4*)(xbuf + 4*halo_idx(r, cp));
                }
            }
        }
    }

    // ---- final: Mreg -> xbuf -> coalesced planar output (1 barrier; no alias with hbuf) ----
    if (act) {
        #pragma unroll
        for (int j = 0; j < RPT; ++j) {
            int rr = r0 + j - TT, cc = cp - TT/2;
            if (rr >= 0 && rr < TILE_R && cc >= 0 && cc < TILE_C/2)
                *(float4*)(xbuf + 4*(rr*(TILE_C/2) + cc)) = Mreg[j];
        }
    }
    __syncthreads();
    {
        float* ou = out + img*2*PLANE;
        float* ov = ou + PLANE;
        for (int k = tid; k < TILE_R*(TILE_C/2); k += NTHR) {
            int r = k >> 5, c2 = k & 31;
            float4 V = *(const float4*)(xbuf + 4*k);
            int q = (rb*TILE_R + r)*WW + cs*TILE_C + 2*c2;
            *(float2*)(ou + q) = make_float2(V.x, V.z);
            *(float2*)(ov + q) = make_float2(V.y, V.w);
        }
    }
}

extern "C" void kernel_launch(void* const* d_in, const int* in_sizes, int n_in,
                              void* d_out, int out_size, void* d_ws, size_t ws_size,
                              hipStream_t stream) {
    const float* x   = (const float*)d_in[0];   // (8,3,256,256) fp32
    const float* est = (const float*)d_in[1];   // (8,2,256,256) fp32
    float* out = (float*)d_out;
    float* ws  = (float*)d_ws;                  // ring slot0 @0, slot1 @8MB, flags @16MB
                                                // flags 0xAA-poisoned each launch: != MAGIC

    dim3 grid(8, WW/TILE_C, HH/TILE_R);         // 256 blocks, all co-resident (1/CU: ~83KB LDS, 16 waves)
    dim3 blk(NTHR);
    hs_mega<<<grid, blk, 0, stream>>>(x, est, out, ws);
}